// Round 11
// baseline (403.891 us; speedup 1.0000x reference)
//
#include <hip/hip_runtime.h>

// ---------------------------------------------------------------------------
// EdgeModel: out = LayerNorm(LReLU(LReLU(LReLU(X@W1+b1)@W2+b2)@W3+b3))
// X = concat[src, dest, edge_attr, u[batch]]  (E=400000, 512 features)
// R11: cross-phase W-frag software pipelining. L1 phase order = {load half-1
//      W-frags} -> {MFMA half-0} -> {load NEXT phase half-0} -> {MFMA half-1}
//      so every W L2-load's ~200cyc latency sits under the previous 32-MFMA
//      cluster. W2/W3 kk=0 frags loaded before the preceding epilogue.
//      Keeps R10 (4 fat K=128 phases, h2->xs, 8 barriers, setprio), R9
//      operand swap, R8 depth-2 input prefetch.
// ---------------------------------------------------------------------------

typedef short bf16x8 __attribute__((ext_vector_type(8)));   // 8 bf16 (guide §3)
typedef float f32x4 __attribute__((ext_vector_type(4)));
typedef unsigned int u32;
typedef unsigned int u32x2 __attribute__((ext_vector_type(2)));

__device__ __forceinline__ unsigned short f2bf(float f) {  // RNE f32->bf16
    union { float f; unsigned u; } v; v.f = f;
    return (unsigned short)((v.u + 0x7fffu + ((v.u >> 16) & 1u)) >> 16);
}
__device__ __forceinline__ u32 cvtpk(float lo, float hi) { // d={bf16(hi),bf16(lo)}
    u32 r;
    asm("v_cvt_pk_bf16_f32 %0, %1, %2" : "=v"(r) : "v"(lo), "v"(hi));
    return r;
}
__device__ __forceinline__ float lrelu(float v) { return v >= 0.f ? v : 0.01f * v; }

// ---------------------------------------------------------------------------
// Pack W (K x N, row-major f32) into bf16 MFMA fragment order (A operand):
// frag(fk,fn): lane l, elem j  ->  W[fk*32 + (l>>4)*8 + j][fn*16 + (l&15)]
// offset(elems) = ((fk*nfn + fn)*64 + l)*8 + j
// ---------------------------------------------------------------------------
__global__ void prep_pack(const float* __restrict__ W1, const float* __restrict__ W2,
                          const float* __restrict__ W3, unsigned short* __restrict__ P) {
    int idx = blockIdx.x * 256 + threadIdx.x;
    const float* W; int N, base;
    if (idx < 131072)      { W = W1; N = 256; base = 0; }
    else if (idx < 196608) { W = W2; N = 256; base = 131072; }
    else if (idx < 229376) { W = W3; N = 128; base = 196608; }
    else return;
    int t = idx - base;
    int j = t & 7, l = (t >> 3) & 63, f = t >> 9;
    int nfn = N >> 4;
    int fk = f / nfn, fn = f - fk * nfn;
    int k = fk * 32 + ((l >> 4) << 3) + j;
    int c = fn * 16 + (l & 15);
    P[idx] = f2bf(W[k * N + c]);
}

// ---------------------------------------------------------------------------
// Main fused kernel. Block = 256 threads (4 waves, feat-split), M_TILE = 64.
// Wave: 64 feats x 64 edges. acc[4][4] (feat-frag x edge-frag), D[feat][edge].
// LDS: xs 2x16KB (dbuf 64x128 bf16 K-slice, swizzled; reused as h2 after L1)
//    + hs 32KB (h1 bf16 -> h3 f32) = 64KB -> 2 blocks/CU.
// ---------------------------------------------------------------------------
template <bool EXACT>
__global__ __launch_bounds__(256) void edge_mlp(
    const float* __restrict__ src, const float* __restrict__ dst,
    const float* __restrict__ ea,  const float* __restrict__ u,
    const int* __restrict__ batch, const unsigned short* __restrict__ Wp,
    const float* __restrict__ b1,  const float* __restrict__ b2,
    const float* __restrict__ b3,  const float* __restrict__ gamma,
    const float* __restrict__ beta, float* __restrict__ out, int E)
{
    __shared__ __align__(16) unsigned char xs[2][64 * 256];  // 2x16KB
    __shared__ __align__(16) unsigned char hs[64 * 512];     // 32KB

    const int tid  = threadIdx.x;
    const int lane = tid & 63;
    const int wn   = tid >> 6;          // wave 0..3 = feature quarter
    const int l15  = lane & 15;
    const int lhi  = lane >> 4;         // 0..3
    const int m0   = blockIdx.x * 64;
    const int ldr8 = tid >> 5;          // 0..7: staging row within 8-row group
    const int ldc5 = tid & 31;          // 0..31: f32x4 column in 128-col slice

    // Hoisted row indices + batch gather (one per 8-row group)
    int grow[8], gb[8];
    #pragma unroll
    for (int p = 0; p < 8; ++p) {
        int rg = m0 + p * 8 + ldr8;
        if (!EXACT) rg = rg < E ? rg : E - 1;
        grow[p] = rg;
        gb[p]   = batch[rg];
    }

    const unsigned short* W1p = Wp;
    const unsigned short* W2p = Wp + 131072;
    const unsigned short* W3p = Wp + 196608;

    const f32x4 zero4 = {0.f, 0.f, 0.f, 0.f};
    f32x4 acc[4][4];                    // [feat-frag][edge-frag]
    #pragma unroll
    for (int m = 0; m < 4; ++m)
        #pragma unroll
        for (int n = 0; n < 4; ++n) acc[m][n] = zero4;

    // Load one full 128-K segment (seg: 0:src 1:dst 2:ea 3:u[batch])
    auto L1LOAD = [&](f32x4 (&pf)[8], int seg) {
        #pragma unroll
        for (int p = 0; p < 8; ++p) {
            const float* gp;
            if (seg == 3) gp = u + (size_t)gb[p] * 128 + ldc5 * 4;
            else {
                const float* bp = (seg == 0) ? src : (seg == 1) ? dst : ea;
                gp = bp + (size_t)grow[p] * 128 + ldc5 * 4;
            }
            pf[p] = *reinterpret_cast<const f32x4*>(gp);
        }
    };
    auto L1WRITE = [&](unsigned char* buf, f32x4 (&pf)[8]) {
        #pragma unroll
        for (int p = 0; p < 8; ++p) {
            int r = p * 8 + ldr8;
            u32x2 h; h.x = cvtpk(pf[p].x, pf[p].y); h.y = cvtpk(pf[p].z, pf[p].w);
            *reinterpret_cast<u32x2*>(
                &buf[r * 256 + ((ldc5 * 8) ^ ((r & 7) << 4))]) = h;
        }
    };
    // Load 8 W1 frags for one K=64 half: frags fk0 (kk=0) and fk0+1 (kk=1)
    auto LOADW1 = [&](bf16x8 (&w)[8], int fk0) {
        #pragma unroll
        for (int m = 0; m < 4; ++m) {
            int fm = wn * 4 + m;
            w[m]     = *reinterpret_cast<const bf16x8*>(
                W1p + (((fk0       * 16 + fm) << 6) + lane) * 8);
            w[4 + m] = *reinterpret_cast<const bf16x8*>(
                W1p + ((((fk0 + 1) * 16 + fm) << 6) + lane) * 8);
        }
    };

    // ============================ layer 1 (K=512) ===========================
    // 4 phases of K=128; input depth-2 prefetch; W-frags pipelined one half
    // ahead so L2 latency hides under the previous 32-MFMA cluster.
    f32x4 pf0[8], pf1[8];
    bf16x8 wP[8];                       // pre-loaded half-0 frags of next phase
    L1LOAD(pf0, 0);
    L1WRITE(xs[0], pf0);
    L1LOAD(pf1, 1);
    LOADW1(wP, 0);                      // phase 0 half 0
    __syncthreads();

    #pragma unroll
    for (int p = 0; p < 4; ++p) {
        const int c = p & 1;
        if (p + 2 < 4) { if (c == 0) L1LOAD(pf0, p + 2); else L1LOAD(pf1, p + 2); }
        if (p + 1 < 4) { if (c == 0) L1WRITE(xs[1], pf1); else L1WRITE(xs[0], pf0); }
        bf16x8 wH[8];
        LOADW1(wH, p * 4 + 2);          // this phase's half-1 frags
        // ---- half 0: MFMA with wP (loaded a full phase ago) ----
        #pragma unroll
        for (int kk = 0; kk < 2; ++kk) {
            const int klo = kk * 32 + lhi * 8;
            bf16x8 xf[4];
            #pragma unroll
            for (int n = 0; n < 4; ++n) {
                int r = n * 16 + l15;
                xf[n] = *reinterpret_cast<const bf16x8*>(
                    &xs[c][r * 256 + ((klo * 2) ^ ((r & 7) << 4))]);
            }
            __builtin_amdgcn_s_setprio(1);
            #pragma unroll
            for (int m = 0; m < 4; ++m)
                #pragma unroll
                for (int n = 0; n < 4; ++n)
                    acc[m][n] = __builtin_amdgcn_mfma_f32_16x16x32_bf16(
                        wP[kk * 4 + m], xf[n], acc[m][n], 0, 0, 0);
            __builtin_amdgcn_s_setprio(0);
        }
        // ---- load next phase's half-0 frags (hides under half-1 MFMAs) ----
        if (p + 1 < 4) LOADW1(wP, (p + 1) * 4);
        // ---- half 1: MFMA with wH ----
        #pragma unroll
        for (int kk = 0; kk < 2; ++kk) {
            const int klo = (2 + kk) * 32 + lhi * 8;
            bf16x8 xf[4];
            #pragma unroll
            for (int n = 0; n < 4; ++n) {
                int r = n * 16 + l15;
                xf[n] = *reinterpret_cast<const bf16x8*>(
                    &xs[c][r * 256 + ((klo * 2) ^ ((r & 7) << 4))]);
            }
            __builtin_amdgcn_s_setprio(1);
            #pragma unroll
            for (int m = 0; m < 4; ++m)
                #pragma unroll
                for (int n = 0; n < 4; ++n)
                    acc[m][n] = __builtin_amdgcn_mfma_f32_16x16x32_bf16(
                        wH[kk * 4 + m], xf[n], acc[m][n], 0, 0, 0);
            __builtin_amdgcn_s_setprio(0);
        }
        __syncthreads();
    }

    // Warm-up W2 kk=0 frags (latency hides under h1 epilogue + barrier)
    bf16x8 wc4[4];
    #pragma unroll
    for (int m = 0; m < 4; ++m)
        wc4[m] = *reinterpret_cast<const bf16x8*>(
            W2p + (((wn * 4 + m) << 6) + lane) * 8);

    // h1 = LReLU(acc + b1) -> hs. Lane holds 4 consecutive feats of one edge.
    #pragma unroll
    for (int m = 0; m < 4; ++m) {
        int f = wn * 64 + m * 16 + lhi * 4;
        f32x4 bb = *reinterpret_cast<const f32x4*>(b1 + f);
        #pragma unroll
        for (int n = 0; n < 4; ++n) {
            int e = n * 16 + l15;
            f32x4 v = acc[m][n];
            u32x2 h;
            h.x = cvtpk(lrelu(v[0] + bb.x), lrelu(v[1] + bb.y));
            h.y = cvtpk(lrelu(v[2] + bb.z), lrelu(v[3] + bb.w));
            *reinterpret_cast<u32x2*>(
                &hs[e * 512 + ((f * 2) ^ ((e & 7) << 4))]) = h;
        }
    }
    __syncthreads();

    // ============================ layer 2 (K=256) ===========================
    // reads h1 (hs), writes h2 into the DEAD xs region (no overwrite barrier).
    unsigned char* h2s = xs[0];          // 32KB contiguous
    #pragma unroll
    for (int m = 0; m < 4; ++m)
        #pragma unroll
        for (int n = 0; n < 4; ++n) acc[m][n] = zero4;
    {   // pipelined W-frags: kk+1 issued before kk's MFMAs (wc4 pre-loaded)
        bf16x8 wn_[4];
        #pragma unroll
        for (int kk = 0; kk < 8; ++kk) {
            if (kk < 7) {
                #pragma unroll
                for (int m = 0; m < 4; ++m)
                    wn_[m] = *reinterpret_cast<const bf16x8*>(
                        W2p + ((((kk + 1) * 16 + wn * 4 + m) << 6) + lane) * 8);
            }
            const int k = kk * 32 + lhi * 8;
            bf16x8 xf[4];
            #pragma unroll
            for (int n = 0; n < 4; ++n) {
                int r = n * 16 + l15;
                xf[n] = *reinterpret_cast<const bf16x8*>(
                    &hs[r * 512 + ((k * 2) ^ ((r & 7) << 4))]);
            }
            __builtin_amdgcn_s_setprio(1);
            #pragma unroll
            for (int m = 0; m < 4; ++m)
                #pragma unroll
                for (int n = 0; n < 4; ++n)
                    acc[m][n] = __builtin_amdgcn_mfma_f32_16x16x32_bf16(
                        wc4[m], xf[n], acc[m][n], 0, 0, 0);
            __builtin_amdgcn_s_setprio(0);
            #pragma unroll
            for (int m = 0; m < 4; ++m) wc4[m] = wn_[m];
        }
    }
    // Warm-up W3 kk=0 frags (latency hides under h2 epilogue + barrier)
    bf16x8 wc2[2];
    #pragma unroll
    for (int m = 0; m < 2; ++m)
        wc2[m] = *reinterpret_cast<const bf16x8*>(
            W3p + (((wn * 2 + m) << 6) + lane) * 8);
    // h2 epilogue -> h2s (disjoint from hs; xs dead): no pre-barrier needed.
    #pragma unroll
    for (int m = 0; m < 4; ++m) {
        int f = wn * 64 + m * 16 + lhi * 4;
        f32x4 bb = *reinterpret_cast<const f32x4*>(b2 + f);
        #pragma unroll
        for (int n = 0; n < 4; ++n) {
            int e = n * 16 + l15;
            f32x4 v = acc[m][n];
            u32x2 h;
            h.x = cvtpk(lrelu(v[0] + bb.x), lrelu(v[1] + bb.y));
            h.y = cvtpk(lrelu(v[2] + bb.z), lrelu(v[3] + bb.w));
            *reinterpret_cast<u32x2*>(
                &h2s[e * 512 + ((f * 2) ^ ((e & 7) << 4))]) = h;
        }
    }
    __syncthreads();   // h2 visible; also: all waves done READING h1 (hs)

    // ============================ layer 3 (K=256, N=128 feats) ==============
    f32x4 acc3[2][4];
    #pragma unroll
    for (int m = 0; m < 2; ++m)
        #pragma unroll
        for (int n = 0; n < 4; ++n) acc3[m][n] = zero4;
    {
        bf16x8 wn_[2];
        #pragma unroll
        for (int kk = 0; kk < 8; ++kk) {
            if (kk < 7) {
                #pragma unroll
                for (int m = 0; m < 2; ++m)
                    wn_[m] = *reinterpret_cast<const bf16x8*>(
                        W3p + ((((kk + 1) * 8 + wn * 2 + m) << 6) + lane) * 8);
            }
            const int k = kk * 32 + lhi * 8;
            bf16x8 xf[4];
            #pragma unroll
            for (int n = 0; n < 4; ++n) {
                int r = n * 16 + l15;
                xf[n] = *reinterpret_cast<const bf16x8*>(
                    &h2s[r * 512 + ((k * 2) ^ ((r & 7) << 4))]);
            }
            __builtin_amdgcn_s_setprio(1);
            #pragma unroll
            for (int m = 0; m < 2; ++m)
                #pragma unroll
                for (int n = 0; n < 4; ++n)
                    acc3[m][n] = __builtin_amdgcn_mfma_f32_16x16x32_bf16(
                        wc2[m], xf[n], acc3[m][n], 0, 0, 0);
            __builtin_amdgcn_s_setprio(0);
            #pragma unroll
            for (int m = 0; m < 2; ++m) wc2[m] = wn_[m];
        }
    }
    // h3 epilogue writes f32 into hs: all h1 reads finished at pre-L3 barrier.
    #pragma unroll
    for (int m = 0; m < 2; ++m) {
        int f = wn * 32 + m * 16 + lhi * 4;
        f32x4 bb = *reinterpret_cast<const f32x4*>(b3 + f);
        #pragma unroll
        for (int n = 0; n < 4; ++n) {
            int e = n * 16 + l15;
            f32x4 v = acc3[m][n];
            f32x4 o;
            o.x = lrelu(v[0] + bb.x); o.y = lrelu(v[1] + bb.y);
            o.z = lrelu(v[2] + bb.z); o.w = lrelu(v[3] + bb.w);
            *reinterpret_cast<f32x4*>(
                &hs[e * 512 + ((f * 4) ^ ((e & 7) << 4))]) = o;
        }
    }
    __syncthreads();

    // ====================== LayerNorm(128) + store ==========================
    {
        const int row = tid >> 2;   // 0..63
        const int sub = tid & 3;    // 4 lanes per row
        f32x4 vv[8];
        float s = 0.f, s2 = 0.f;
        #pragma unroll
        for (int j = 0; j < 8; ++j) {
            int cb = j * 16 + sub * 4;
            f32x4 t = *reinterpret_cast<const f32x4*>(
                &hs[row * 512 + ((cb * 4) ^ ((row & 7) << 4))]);
            vv[j] = t;
            s  += t.x + t.y + t.z + t.w;
            s2 += t.x * t.x + t.y * t.y + t.z * t.z + t.w * t.w;
        }
        s  += __shfl_xor(s, 1);  s  += __shfl_xor(s, 2);
        s2 += __shfl_xor(s2, 1); s2 += __shfl_xor(s2, 2);
        const float mean = s * (1.f / 128.f);
        const float var  = s2 * (1.f / 128.f) - mean * mean;
        const float rstd = rsqrtf(var + 1e-5f);
        const int rg = m0 + row;
        if (EXACT || rg < E) {
            float* op = out + (size_t)rg * 128;
            #pragma unroll
            for (int j = 0; j < 8; ++j) {
                int cb = j * 16 + sub * 4;
                f32x4 g  = *reinterpret_cast<const f32x4*>(gamma + cb);
                f32x4 be = *reinterpret_cast<const f32x4*>(beta + cb);
                f32x4 o;
                o.x = (vv[j].x - mean) * rstd * g.x + be.x;
                o.y = (vv[j].y - mean) * rstd * g.y + be.y;
                o.z = (vv[j].z - mean) * rstd * g.z + be.z;
                o.w = (vv[j].w - mean) * rstd * g.w + be.w;
                *reinterpret_cast<f32x4*>(op + cb) = o;
            }
        }
    }
}

extern "C" void kernel_launch(void* const* d_in, const int* in_sizes, int n_in,
                              void* d_out, int out_size, void* d_ws, size_t ws_size,
                              hipStream_t stream) {
    const float* src  = (const float*)d_in[0];
    const float* dst  = (const float*)d_in[1];
    const float* ea   = (const float*)d_in[2];
    const float* u    = (const float*)d_in[3];
    const int*   bat  = (const int*)d_in[4];
    const float* W1   = (const float*)d_in[5];
    const float* b1   = (const float*)d_in[6];
    const float* W2   = (const float*)d_in[7];
    const float* b2   = (const float*)d_in[8];
    const float* W3   = (const float*)d_in[9];
    const float* b3   = (const float*)d_in[10];
    const float* gam  = (const float*)d_in[11];
    const float* bet  = (const float*)d_in[12];
    float* out = (float*)d_out;
    unsigned short* Wp = (unsigned short*)d_ws;   // 458752 B used

    const int E = in_sizes[0] / 128;

    prep_pack<<<896, 256, 0, stream>>>(W1, W2, W3, Wp);
    const int nblk = (E + 63) / 64;
    if ((E & 63) == 0)
        edge_mlp<true><<<nblk, 256, 0, stream>>>(src, dst, ea, u, bat, Wp,
                                                 b1, b2, b3, gam, bet, out, E);
    else
        edge_mlp<false><<<nblk, 256, 0, stream>>>(src, dst, ea, u, bat, Wp,
                                                  b1, b2, b3, gam, bet, out, E);
}

// Round 12
// 294.435 us; speedup vs baseline: 1.3718x; 1.3718x over previous
//
#include <hip/hip_runtime.h>

// ---------------------------------------------------------------------------
// EdgeModel: out = LayerNorm(LReLU(LReLU(LReLU(X@W1+b1)@W2+b2)@W3+b3))
// X = concat[src, dest, edge_attr, u[batch]]  (E=400000, 512 features)
// R12: REVERT R11's L1 W-pipelining (+24 VGPR crossed occupancy cliff,
//      22.4->11.8%, 291->404us). Base = R10 (best, 291us). Added, both
//      register-safe (outside L1 pressure peak):
//      (1) W2/W3 kk=0 warm-up moved before the preceding epilogue (pf dead).
//      (2) FUSED LayerNorm: h3 stays in registers; per-edge partials via
//          shfl_xor(16/32) + 2KB lnp[edge][wave] buffer + 1 barrier; direct
//          global stores. Removes 64KB LDS round-trip + 1 barrier.
// ---------------------------------------------------------------------------

typedef short bf16x8 __attribute__((ext_vector_type(8)));   // 8 bf16 (guide §3)
typedef float f32x4 __attribute__((ext_vector_type(4)));
typedef unsigned int u32;
typedef unsigned int u32x2 __attribute__((ext_vector_type(2)));

__device__ __forceinline__ unsigned short f2bf(float f) {  // RNE f32->bf16
    union { float f; unsigned u; } v; v.f = f;
    return (unsigned short)((v.u + 0x7fffu + ((v.u >> 16) & 1u)) >> 16);
}
__device__ __forceinline__ u32 cvtpk(float lo, float hi) { // d={bf16(hi),bf16(lo)}
    u32 r;
    asm("v_cvt_pk_bf16_f32 %0, %1, %2" : "=v"(r) : "v"(lo), "v"(hi));
    return r;
}
__device__ __forceinline__ float lrelu(float v) { return v >= 0.f ? v : 0.01f * v; }

// ---------------------------------------------------------------------------
// Pack W (K x N, row-major f32) into bf16 MFMA fragment order (A operand):
// frag(fk,fn): lane l, elem j  ->  W[fk*32 + (l>>4)*8 + j][fn*16 + (l&15)]
// offset(elems) = ((fk*nfn + fn)*64 + l)*8 + j
// ---------------------------------------------------------------------------
__global__ void prep_pack(const float* __restrict__ W1, const float* __restrict__ W2,
                          const float* __restrict__ W3, unsigned short* __restrict__ P) {
    int idx = blockIdx.x * 256 + threadIdx.x;
    const float* W; int N, base;
    if (idx < 131072)      { W = W1; N = 256; base = 0; }
    else if (idx < 196608) { W = W2; N = 256; base = 131072; }
    else if (idx < 229376) { W = W3; N = 128; base = 196608; }
    else return;
    int t = idx - base;
    int j = t & 7, l = (t >> 3) & 63, f = t >> 9;
    int nfn = N >> 4;
    int fk = f / nfn, fn = f - fk * nfn;
    int k = fk * 32 + ((l >> 4) << 3) + j;
    int c = fn * 16 + (l & 15);
    P[idx] = f2bf(W[k * N + c]);
}

// ---------------------------------------------------------------------------
// Main fused kernel. Block = 256 threads (4 waves, feat-split), M_TILE = 64.
// Wave: 64 feats x 64 edges. acc[4][4] (feat-frag x edge-frag), D[feat][edge].
// LDS: xs 2x16KB (dbuf 64x128 bf16 K-slice, swizzled; reused as h2 after L1)
//    + hs 32KB (h1 bf16) + lnp 2KB = 66KB -> 2 blocks/CU.
// ---------------------------------------------------------------------------
template <bool EXACT>
__global__ __launch_bounds__(256) void edge_mlp(
    const float* __restrict__ src, const float* __restrict__ dst,
    const float* __restrict__ ea,  const float* __restrict__ u,
    const int* __restrict__ batch, const unsigned short* __restrict__ Wp,
    const float* __restrict__ b1,  const float* __restrict__ b2,
    const float* __restrict__ b3,  const float* __restrict__ gamma,
    const float* __restrict__ beta, float* __restrict__ out, int E)
{
    __shared__ __align__(16) unsigned char xs[2][64 * 256];  // 2x16KB
    __shared__ __align__(16) unsigned char hs[64 * 512];     // 32KB (h1)
    __shared__ __align__(16) float lnp[64][4][2];            // 2KB partials

    const int tid  = threadIdx.x;
    const int lane = tid & 63;
    const int wn   = tid >> 6;          // wave 0..3 = feature quarter
    const int l15  = lane & 15;
    const int lhi  = lane >> 4;         // 0..3
    const int m0   = blockIdx.x * 64;
    const int ldr8 = tid >> 5;          // 0..7: staging row within 8-row group
    const int ldc5 = tid & 31;          // 0..31: f32x4 column in 128-col slice

    // Hoisted row indices + batch gather (one per 8-row group)
    int grow[8], gb[8];
    #pragma unroll
    for (int p = 0; p < 8; ++p) {
        int rg = m0 + p * 8 + ldr8;
        if (!EXACT) rg = rg < E ? rg : E - 1;
        grow[p] = rg;
        gb[p]   = batch[rg];
    }

    const unsigned short* W1p = Wp;
    const unsigned short* W2p = Wp + 131072;
    const unsigned short* W3p = Wp + 196608;

    const f32x4 zero4 = {0.f, 0.f, 0.f, 0.f};
    f32x4 acc[4][4];                    // [feat-frag][edge-frag]
    #pragma unroll
    for (int m = 0; m < 4; ++m)
        #pragma unroll
        for (int n = 0; n < 4; ++n) acc[m][n] = zero4;

    // Load one full 128-K segment (seg: 0:src 1:dst 2:ea 3:u[batch])
    auto L1LOAD = [&](f32x4 (&pf)[8], int seg) {
        #pragma unroll
        for (int p = 0; p < 8; ++p) {
            const float* gp;
            if (seg == 3) gp = u + (size_t)gb[p] * 128 + ldc5 * 4;
            else {
                const float* bp = (seg == 0) ? src : (seg == 1) ? dst : ea;
                gp = bp + (size_t)grow[p] * 128 + ldc5 * 4;
            }
            pf[p] = *reinterpret_cast<const f32x4*>(gp);
        }
    };
    auto L1WRITE = [&](unsigned char* buf, f32x4 (&pf)[8]) {
        #pragma unroll
        for (int p = 0; p < 8; ++p) {
            int r = p * 8 + ldr8;
            u32x2 h; h.x = cvtpk(pf[p].x, pf[p].y); h.y = cvtpk(pf[p].z, pf[p].w);
            *reinterpret_cast<u32x2*>(
                &buf[r * 256 + ((ldc5 * 8) ^ ((r & 7) << 4))]) = h;
        }
    };

    // ============================ layer 1 (K=512) ===========================
    // 4 phases of K=128; depth-2 input prefetch (R8); per-half upfront W-frags
    // (R10 -- NOT the R11 cross-phase form, which cost occupancy).
    f32x4 pf0[8], pf1[8];
    L1LOAD(pf0, 0);
    L1WRITE(xs[0], pf0);
    L1LOAD(pf1, 1);
    __syncthreads();

    #pragma unroll
    for (int p = 0; p < 4; ++p) {
        const int c = p & 1;
        if (p + 2 < 4) { if (c == 0) L1LOAD(pf0, p + 2); else L1LOAD(pf1, p + 2); }
        if (p + 1 < 4) { if (c == 0) L1WRITE(xs[1], pf1); else L1WRITE(xs[0], pf0); }
        #pragma unroll
        for (int h = 0; h < 2; ++h) {   // two K=64 halves; W-frags 2 kk upfront
            bf16x8 wA[4], wB[4];
            const int fkA = p * 4 + h * 2, fkB = fkA + 1;
            #pragma unroll
            for (int m = 0; m < 4; ++m) {
                int fm = wn * 4 + m;
                wA[m] = *reinterpret_cast<const bf16x8*>(
                    W1p + (((fkA * 16 + fm) << 6) + lane) * 8);
                wB[m] = *reinterpret_cast<const bf16x8*>(
                    W1p + (((fkB * 16 + fm) << 6) + lane) * 8);
            }
            #pragma unroll
            for (int kk = 0; kk < 2; ++kk) {
                const int klo = (h * 2 + kk) * 32 + lhi * 8;
                bf16x8 xf[4];
                #pragma unroll
                for (int n = 0; n < 4; ++n) {
                    int r = n * 16 + l15;
                    xf[n] = *reinterpret_cast<const bf16x8*>(
                        &xs[c][r * 256 + ((klo * 2) ^ ((r & 7) << 4))]);
                }
                __builtin_amdgcn_s_setprio(1);
                #pragma unroll
                for (int m = 0; m < 4; ++m)
                    #pragma unroll
                    for (int n = 0; n < 4; ++n)
                        acc[m][n] = __builtin_amdgcn_mfma_f32_16x16x32_bf16(
                            kk == 0 ? wA[m] : wB[m], xf[n], acc[m][n], 0, 0, 0);
                __builtin_amdgcn_s_setprio(0);
            }
        }
        __syncthreads();
    }

    // W2 kk=0 warm-up: pf0/pf1 dead here -> register-safe; latency hides
    // under the h1 epilogue + barrier.
    bf16x8 wc4[4];
    #pragma unroll
    for (int m = 0; m < 4; ++m)
        wc4[m] = *reinterpret_cast<const bf16x8*>(
            W2p + (((wn * 4 + m) << 6) + lane) * 8);

    // h1 = LReLU(acc + b1) -> hs. Lane holds 4 consecutive feats of one edge.
    #pragma unroll
    for (int m = 0; m < 4; ++m) {
        int f = wn * 64 + m * 16 + lhi * 4;
        f32x4 bb = *reinterpret_cast<const f32x4*>(b1 + f);
        #pragma unroll
        for (int n = 0; n < 4; ++n) {
            int e = n * 16 + l15;
            f32x4 v = acc[m][n];
            u32x2 h;
            h.x = cvtpk(lrelu(v[0] + bb.x), lrelu(v[1] + bb.y));
            h.y = cvtpk(lrelu(v[2] + bb.z), lrelu(v[3] + bb.w));
            *reinterpret_cast<u32x2*>(
                &hs[e * 512 + ((f * 2) ^ ((e & 7) << 4))]) = h;
        }
    }
    __syncthreads();

    // ============================ layer 2 (K=256) ===========================
    // reads h1 (hs), writes h2 into the DEAD xs region (no overwrite barrier).
    unsigned char* h2s = xs[0];          // 32KB contiguous
    #pragma unroll
    for (int m = 0; m < 4; ++m)
        #pragma unroll
        for (int n = 0; n < 4; ++n) acc[m][n] = zero4;
    {   // pipelined W-frags: kk+1 issued before kk's MFMAs (wc4 pre-loaded)
        bf16x8 wn_[4];
        #pragma unroll
        for (int kk = 0; kk < 8; ++kk) {
            if (kk < 7) {
                #pragma unroll
                for (int m = 0; m < 4; ++m)
                    wn_[m] = *reinterpret_cast<const bf16x8*>(
                        W2p + ((((kk + 1) * 16 + wn * 4 + m) << 6) + lane) * 8);
            }
            const int k = kk * 32 + lhi * 8;
            bf16x8 xf[4];
            #pragma unroll
            for (int n = 0; n < 4; ++n) {
                int r = n * 16 + l15;
                xf[n] = *reinterpret_cast<const bf16x8*>(
                    &hs[r * 512 + ((k * 2) ^ ((r & 7) << 4))]);
            }
            __builtin_amdgcn_s_setprio(1);
            #pragma unroll
            for (int m = 0; m < 4; ++m)
                #pragma unroll
                for (int n = 0; n < 4; ++n)
                    acc[m][n] = __builtin_amdgcn_mfma_f32_16x16x32_bf16(
                        wc4[m], xf[n], acc[m][n], 0, 0, 0);
            __builtin_amdgcn_s_setprio(0);
            #pragma unroll
            for (int m = 0; m < 4; ++m) wc4[m] = wn_[m];
        }
    }
    // W3 kk=0 warm-up (register-safe here; hides under h2 epilogue + barrier)
    bf16x8 wc2[2];
    #pragma unroll
    for (int m = 0; m < 2; ++m)
        wc2[m] = *reinterpret_cast<const bf16x8*>(
            W3p + (((wn * 2 + m) << 6) + lane) * 8);
    // h2 epilogue -> h2s (disjoint from hs; xs dead): no pre-barrier needed.
    #pragma unroll
    for (int m = 0; m < 4; ++m) {
        int f = wn * 64 + m * 16 + lhi * 4;
        f32x4 bb = *reinterpret_cast<const f32x4*>(b2 + f);
        #pragma unroll
        for (int n = 0; n < 4; ++n) {
            int e = n * 16 + l15;
            f32x4 v = acc[m][n];
            u32x2 h;
            h.x = cvtpk(lrelu(v[0] + bb.x), lrelu(v[1] + bb.y));
            h.y = cvtpk(lrelu(v[2] + bb.z), lrelu(v[3] + bb.w));
            *reinterpret_cast<u32x2*>(
                &h2s[e * 512 + ((f * 2) ^ ((e & 7) << 4))]) = h;
        }
    }
    __syncthreads();   // h2 visible; also: all waves done READING h1 (hs)

    // ============================ layer 3 (K=256, N=128 feats) ==============
    f32x4 acc3[2][4];
    #pragma unroll
    for (int m = 0; m < 2; ++m)
        #pragma unroll
        for (int n = 0; n < 4; ++n) acc3[m][n] = zero4;
    {
        bf16x8 wn_[2];
        #pragma unroll
        for (int kk = 0; kk < 8; ++kk) {
            if (kk < 7) {
                #pragma unroll
                for (int m = 0; m < 2; ++m)
                    wn_[m] = *reinterpret_cast<const bf16x8*>(
                        W3p + ((((kk + 1) * 8 + wn * 2 + m) << 6) + lane) * 8);
            }
            const int k = kk * 32 + lhi * 8;
            bf16x8 xf[4];
            #pragma unroll
            for (int n = 0; n < 4; ++n) {
                int r = n * 16 + l15;
                xf[n] = *reinterpret_cast<const bf16x8*>(
                    &h2s[r * 512 + ((k * 2) ^ ((r & 7) << 4))]);
            }
            __builtin_amdgcn_s_setprio(1);
            #pragma unroll
            for (int m = 0; m < 2; ++m)
                #pragma unroll
                for (int n = 0; n < 4; ++n)
                    acc3[m][n] = __builtin_amdgcn_mfma_f32_16x16x32_bf16(
                        wc2[m], xf[n], acc3[m][n], 0, 0, 0);
            __builtin_amdgcn_s_setprio(0);
            #pragma unroll
            for (int m = 0; m < 2; ++m) wc2[m] = wn_[m];
        }
    }

    // ================= fused LayerNorm epilogue (h3 in registers) ===========
    // h3 = LReLU(acc3 + b3) in place
    #pragma unroll
    for (int m = 0; m < 2; ++m) {
        int f = wn * 32 + m * 16 + lhi * 4;
        f32x4 bb = *reinterpret_cast<const f32x4*>(b3 + f);
        #pragma unroll
        for (int n = 0; n < 4; ++n) {
            f32x4 v = acc3[m][n];
            v.x = lrelu(v.x + bb.x); v.y = lrelu(v.y + bb.y);
            v.z = lrelu(v.z + bb.z); v.w = lrelu(v.w + bb.w);
            acc3[m][n] = v;
        }
    }
    // per-edge partials over this wave's 32 feats: reduce across lhi (bits 4,5)
    #pragma unroll
    for (int n = 0; n < 4; ++n) {
        float s = 0.f, s2 = 0.f;
        #pragma unroll
        for (int m = 0; m < 2; ++m) {
            f32x4 v = acc3[m][n];
            s  += v.x + v.y + v.z + v.w;
            s2 += v.x * v.x + v.y * v.y + v.z * v.z + v.w * v.w;
        }
        s  += __shfl_xor(s, 16);  s  += __shfl_xor(s, 32);
        s2 += __shfl_xor(s2, 16); s2 += __shfl_xor(s2, 32);
        if (lhi == 0) {
            lnp[n * 16 + l15][wn][0] = s;
            lnp[n * 16 + l15][wn][1] = s2;
        }
    }
    __syncthreads();   // partials visible (h2s reads also complete)
    {
        const int f0 = wn * 32 + lhi * 4;
        const int f1 = f0 + 16;
        f32x4 gam0 = *reinterpret_cast<const f32x4*>(gamma + f0);
        f32x4 gam1 = *reinterpret_cast<const f32x4*>(gamma + f1);
        f32x4 bet0 = *reinterpret_cast<const f32x4*>(beta + f0);
        f32x4 bet1 = *reinterpret_cast<const f32x4*>(beta + f1);
        #pragma unroll
        for (int n = 0; n < 4; ++n) {
            int e = n * 16 + l15;
            f32x4 pa = *reinterpret_cast<const f32x4*>(&lnp[e][0][0]);
            f32x4 pb = *reinterpret_cast<const f32x4*>(&lnp[e][2][0]);
            float s    = pa.x + pa.z + pb.x + pb.z;
            float s2   = pa.y + pa.w + pb.y + pb.w;
            float mean = s * (1.f / 128.f);
            float var  = s2 * (1.f / 128.f) - mean * mean;
            float rstd = rsqrtf(var + 1e-5f);
            int rg = m0 + e;
            if (EXACT || rg < E) {
                float* op = out + (size_t)rg * 128;
                f32x4 v0 = acc3[0][n], v1 = acc3[1][n];
                f32x4 o0, o1;
                o0.x = (v0.x - mean) * rstd * gam0.x + bet0.x;
                o0.y = (v0.y - mean) * rstd * gam0.y + bet0.y;
                o0.z = (v0.z - mean) * rstd * gam0.z + bet0.z;
                o0.w = (v0.w - mean) * rstd * gam0.w + bet0.w;
                o1.x = (v1.x - mean) * rstd * gam1.x + bet1.x;
                o1.y = (v1.y - mean) * rstd * gam1.y + bet1.y;
                o1.z = (v1.z - mean) * rstd * gam1.z + bet1.z;
                o1.w = (v1.w - mean) * rstd * gam1.w + bet1.w;
                *reinterpret_cast<f32x4*>(op + f0) = o0;
                *reinterpret_cast<f32x4*>(op + f1) = o1;
            }
        }
    }
}

extern "C" void kernel_launch(void* const* d_in, const int* in_sizes, int n_in,
                              void* d_out, int out_size, void* d_ws, size_t ws_size,
                              hipStream_t stream) {
    const float* src  = (const float*)d_in[0];
    const float* dst  = (const float*)d_in[1];
    const float* ea   = (const float*)d_in[2];
    const float* u    = (const float*)d_in[3];
    const int*   bat  = (const int*)d_in[4];
    const float* W1   = (const float*)d_in[5];
    const float* b1   = (const float*)d_in[6];
    const float* W2   = (const float*)d_in[7];
    const float* b2   = (const float*)d_in[8];
    const float* W3   = (const float*)d_in[9];
    const float* b3   = (const float*)d_in[10];
    const float* gam  = (const float*)d_in[11];
    const float* bet  = (const float*)d_in[12];
    float* out = (float*)d_out;
    unsigned short* Wp = (unsigned short*)d_ws;   // 458752 B used

    const int E = in_sizes[0] / 128;

    prep_pack<<<896, 256, 0, stream>>>(W1, W2, W3, Wp);
    const int nblk = (E + 63) / 64;
    if ((E & 63) == 0)
        edge_mlp<true><<<nblk, 256, 0, stream>>>(src, dst, ea, u, bat, Wp,
                                                 b1, b2, b3, gam, bet, out, E);
    else
        edge_mlp<false><<<nblk, 256, 0, stream>>>(src, dst, ea, u, bat, Wp,
                                                  b1, b2, b3, gam, bet, out, E);
}

// Round 13
// 294.382 us; speedup vs baseline: 1.3720x; 1.0002x over previous
//
#include <hip/hip_runtime.h>

// ---------------------------------------------------------------------------
// EdgeModel: out = LayerNorm(LReLU(LReLU(LReLU(X@W1+b1)@W2+b2)@W3+b3))
// X = concat[src, dest, edge_attr, u[batch]]  (E=400000, 512 features)
// R13: 4-bit XOR swizzle. Bank math: rows are 256B/512B (bank-aligned), k
//      contributes offset bits 4-7; old (row&7)<<4 randomized only bits 4-6
//      -> 8 distinct 16B slots for 64 lanes = 8-way conflict (2.94x, m136)
//      on every xf ds_read_b128. (row&15)<<4 -> 16 slots = 4-way (1.58x).
//      Base = R12 (fused LN, W2/W3 warm-ups, R10 phases, R9 swap, R8 pf).
// ---------------------------------------------------------------------------

typedef short bf16x8 __attribute__((ext_vector_type(8)));   // 8 bf16 (guide §3)
typedef float f32x4 __attribute__((ext_vector_type(4)));
typedef unsigned int u32;
typedef unsigned int u32x2 __attribute__((ext_vector_type(2)));

__device__ __forceinline__ unsigned short f2bf(float f) {  // RNE f32->bf16
    union { float f; unsigned u; } v; v.f = f;
    return (unsigned short)((v.u + 0x7fffu + ((v.u >> 16) & 1u)) >> 16);
}
__device__ __forceinline__ u32 cvtpk(float lo, float hi) { // d={bf16(hi),bf16(lo)}
    u32 r;
    asm("v_cvt_pk_bf16_f32 %0, %1, %2" : "=v"(r) : "v"(lo), "v"(hi));
    return r;
}
__device__ __forceinline__ float lrelu(float v) { return v >= 0.f ? v : 0.01f * v; }

// ---------------------------------------------------------------------------
// Pack W (K x N, row-major f32) into bf16 MFMA fragment order (A operand):
// frag(fk,fn): lane l, elem j  ->  W[fk*32 + (l>>4)*8 + j][fn*16 + (l&15)]
// offset(elems) = ((fk*nfn + fn)*64 + l)*8 + j
// ---------------------------------------------------------------------------
__global__ void prep_pack(const float* __restrict__ W1, const float* __restrict__ W2,
                          const float* __restrict__ W3, unsigned short* __restrict__ P) {
    int idx = blockIdx.x * 256 + threadIdx.x;
    const float* W; int N, base;
    if (idx < 131072)      { W = W1; N = 256; base = 0; }
    else if (idx < 196608) { W = W2; N = 256; base = 131072; }
    else if (idx < 229376) { W = W3; N = 128; base = 196608; }
    else return;
    int t = idx - base;
    int j = t & 7, l = (t >> 3) & 63, f = t >> 9;
    int nfn = N >> 4;
    int fk = f / nfn, fn = f - fk * nfn;
    int k = fk * 32 + ((l >> 4) << 3) + j;
    int c = fn * 16 + (l & 15);
    P[idx] = f2bf(W[k * N + c]);
}

// ---------------------------------------------------------------------------
// Main fused kernel. Block = 256 threads (4 waves, feat-split), M_TILE = 64.
// Wave: 64 feats x 64 edges. acc[4][4] (feat-frag x edge-frag), D[feat][edge].
// LDS: xs 2x16KB (dbuf 64x128 bf16 K-slice; reused as h2 after L1)
//    + hs 32KB (h1 bf16) + lnp 2KB = 66KB -> 2 blocks/CU.
// ---------------------------------------------------------------------------
template <bool EXACT>
__global__ __launch_bounds__(256) void edge_mlp(
    const float* __restrict__ src, const float* __restrict__ dst,
    const float* __restrict__ ea,  const float* __restrict__ u,
    const int* __restrict__ batch, const unsigned short* __restrict__ Wp,
    const float* __restrict__ b1,  const float* __restrict__ b2,
    const float* __restrict__ b3,  const float* __restrict__ gamma,
    const float* __restrict__ beta, float* __restrict__ out, int E)
{
    __shared__ __align__(16) unsigned char xs[2][64 * 256];  // 2x16KB
    __shared__ __align__(16) unsigned char hs[64 * 512];     // 32KB (h1)
    __shared__ __align__(16) float lnp[64][4][2];            // 2KB partials

    const int tid  = threadIdx.x;
    const int lane = tid & 63;
    const int wn   = tid >> 6;          // wave 0..3 = feature quarter
    const int l15  = lane & 15;
    const int lhi  = lane >> 4;         // 0..3
    const int m0   = blockIdx.x * 64;
    const int ldr8 = tid >> 5;          // 0..7: staging row within 8-row group
    const int ldc5 = tid & 31;          // 0..31: f32x4 column in 128-col slice

    // Hoisted row indices + batch gather (one per 8-row group)
    int grow[8], gb[8];
    #pragma unroll
    for (int p = 0; p < 8; ++p) {
        int rg = m0 + p * 8 + ldr8;
        if (!EXACT) rg = rg < E ? rg : E - 1;
        grow[p] = rg;
        gb[p]   = batch[rg];
    }

    const unsigned short* W1p = Wp;
    const unsigned short* W2p = Wp + 131072;
    const unsigned short* W3p = Wp + 196608;

    const f32x4 zero4 = {0.f, 0.f, 0.f, 0.f};
    f32x4 acc[4][4];                    // [feat-frag][edge-frag]
    #pragma unroll
    for (int m = 0; m < 4; ++m)
        #pragma unroll
        for (int n = 0; n < 4; ++n) acc[m][n] = zero4;

    // Load one full 128-K segment (seg: 0:src 1:dst 2:ea 3:u[batch])
    auto L1LOAD = [&](f32x4 (&pf)[8], int seg) {
        #pragma unroll
        for (int p = 0; p < 8; ++p) {
            const float* gp;
            if (seg == 3) gp = u + (size_t)gb[p] * 128 + ldc5 * 4;
            else {
                const float* bp = (seg == 0) ? src : (seg == 1) ? dst : ea;
                gp = bp + (size_t)grow[p] * 128 + ldc5 * 4;
            }
            pf[p] = *reinterpret_cast<const f32x4*>(gp);
        }
    };
    auto L1WRITE = [&](unsigned char* buf, f32x4 (&pf)[8]) {
        #pragma unroll
        for (int p = 0; p < 8; ++p) {
            int r = p * 8 + ldr8;
            u32x2 h; h.x = cvtpk(pf[p].x, pf[p].y); h.y = cvtpk(pf[p].z, pf[p].w);
            *reinterpret_cast<u32x2*>(
                &buf[r * 256 + ((ldc5 * 8) ^ ((r & 15) << 4))]) = h;
        }
    };

    // ============================ layer 1 (K=512) ===========================
    // 4 phases of K=128; depth-2 input prefetch; per-half upfront W-frags.
    f32x4 pf0[8], pf1[8];
    L1LOAD(pf0, 0);
    L1WRITE(xs[0], pf0);
    L1LOAD(pf1, 1);
    __syncthreads();

    #pragma unroll
    for (int p = 0; p < 4; ++p) {
        const int c = p & 1;
        if (p + 2 < 4) { if (c == 0) L1LOAD(pf0, p + 2); else L1LOAD(pf1, p + 2); }
        if (p + 1 < 4) { if (c == 0) L1WRITE(xs[1], pf1); else L1WRITE(xs[0], pf0); }
        #pragma unroll
        for (int h = 0; h < 2; ++h) {   // two K=64 halves; W-frags 2 kk upfront
            bf16x8 wA[4], wB[4];
            const int fkA = p * 4 + h * 2, fkB = fkA + 1;
            #pragma unroll
            for (int m = 0; m < 4; ++m) {
                int fm = wn * 4 + m;
                wA[m] = *reinterpret_cast<const bf16x8*>(
                    W1p + (((fkA * 16 + fm) << 6) + lane) * 8);
                wB[m] = *reinterpret_cast<const bf16x8*>(
                    W1p + (((fkB * 16 + fm) << 6) + lane) * 8);
            }
            #pragma unroll
            for (int kk = 0; kk < 2; ++kk) {
                const int klo = (h * 2 + kk) * 32 + lhi * 8;
                bf16x8 xf[4];
                #pragma unroll
                for (int n = 0; n < 4; ++n) {
                    int r = n * 16 + l15;
                    xf[n] = *reinterpret_cast<const bf16x8*>(
                        &xs[c][r * 256 + ((klo * 2) ^ ((r & 15) << 4))]);
                }
                __builtin_amdgcn_s_setprio(1);
                #pragma unroll
                for (int m = 0; m < 4; ++m)
                    #pragma unroll
                    for (int n = 0; n < 4; ++n)
                        acc[m][n] = __builtin_amdgcn_mfma_f32_16x16x32_bf16(
                            kk == 0 ? wA[m] : wB[m], xf[n], acc[m][n], 0, 0, 0);
                __builtin_amdgcn_s_setprio(0);
            }
        }
        __syncthreads();
    }

    // W2 kk=0 warm-up: pf0/pf1 dead here -> register-safe; latency hides
    // under the h1 epilogue + barrier.
    bf16x8 wc4[4];
    #pragma unroll
    for (int m = 0; m < 4; ++m)
        wc4[m] = *reinterpret_cast<const bf16x8*>(
            W2p + (((wn * 4 + m) << 6) + lane) * 8);

    // h1 = LReLU(acc + b1) -> hs. Lane holds 4 consecutive feats of one edge.
    #pragma unroll
    for (int m = 0; m < 4; ++m) {
        int f = wn * 64 + m * 16 + lhi * 4;
        f32x4 bb = *reinterpret_cast<const f32x4*>(b1 + f);
        #pragma unroll
        for (int n = 0; n < 4; ++n) {
            int e = n * 16 + l15;
            f32x4 v = acc[m][n];
            u32x2 h;
            h.x = cvtpk(lrelu(v[0] + bb.x), lrelu(v[1] + bb.y));
            h.y = cvtpk(lrelu(v[2] + bb.z), lrelu(v[3] + bb.w));
            *reinterpret_cast<u32x2*>(
                &hs[e * 512 + ((f * 2) ^ ((e & 15) << 4))]) = h;
        }
    }
    __syncthreads();

    // ============================ layer 2 (K=256) ===========================
    // reads h1 (hs), writes h2 into the DEAD xs region (no overwrite barrier).
    unsigned char* h2s = xs[0];          // 32KB contiguous
    #pragma unroll
    for (int m = 0; m < 4; ++m)
        #pragma unroll
        for (int n = 0; n < 4; ++n) acc[m][n] = zero4;
    {   // pipelined W-frags: kk+1 issued before kk's MFMAs (wc4 pre-loaded)
        bf16x8 wn_[4];
        #pragma unroll
        for (int kk = 0; kk < 8; ++kk) {
            if (kk < 7) {
                #pragma unroll
                for (int m = 0; m < 4; ++m)
                    wn_[m] = *reinterpret_cast<const bf16x8*>(
                        W2p + ((((kk + 1) * 16 + wn * 4 + m) << 6) + lane) * 8);
            }
            const int k = kk * 32 + lhi * 8;
            bf16x8 xf[4];
            #pragma unroll
            for (int n = 0; n < 4; ++n) {
                int r = n * 16 + l15;
                xf[n] = *reinterpret_cast<const bf16x8*>(
                    &hs[r * 512 + ((k * 2) ^ ((r & 15) << 4))]);
            }
            __builtin_amdgcn_s_setprio(1);
            #pragma unroll
            for (int m = 0; m < 4; ++m)
                #pragma unroll
                for (int n = 0; n < 4; ++n)
                    acc[m][n] = __builtin_amdgcn_mfma_f32_16x16x32_bf16(
                        wc4[m], xf[n], acc[m][n], 0, 0, 0);
            __builtin_amdgcn_s_setprio(0);
            #pragma unroll
            for (int m = 0; m < 4; ++m) wc4[m] = wn_[m];
        }
    }
    // W3 kk=0 warm-up (register-safe here; hides under h2 epilogue + barrier)
    bf16x8 wc2[2];
    #pragma unroll
    for (int m = 0; m < 2; ++m)
        wc2[m] = *reinterpret_cast<const bf16x8*>(
            W3p + (((wn * 2 + m) << 6) + lane) * 8);
    // h2 epilogue -> h2s (disjoint from hs; xs dead): no pre-barrier needed.
    #pragma unroll
    for (int m = 0; m < 4; ++m) {
        int f = wn * 64 + m * 16 + lhi * 4;
        f32x4 bb = *reinterpret_cast<const f32x4*>(b2 + f);
        #pragma unroll
        for (int n = 0; n < 4; ++n) {
            int e = n * 16 + l15;
            f32x4 v = acc[m][n];
            u32x2 h;
            h.x = cvtpk(lrelu(v[0] + bb.x), lrelu(v[1] + bb.y));
            h.y = cvtpk(lrelu(v[2] + bb.z), lrelu(v[3] + bb.w));
            *reinterpret_cast<u32x2*>(
                &h2s[e * 512 + ((f * 2) ^ ((e & 15) << 4))]) = h;
        }
    }
    __syncthreads();   // h2 visible; also: all waves done READING h1 (hs)

    // ============================ layer 3 (K=256, N=128 feats) ==============
    f32x4 acc3[2][4];
    #pragma unroll
    for (int m = 0; m < 2; ++m)
        #pragma unroll
        for (int n = 0; n < 4; ++n) acc3[m][n] = zero4;
    {
        bf16x8 wn_[2];
        #pragma unroll
        for (int kk = 0; kk < 8; ++kk) {
            if (kk < 7) {
                #pragma unroll
                for (int m = 0; m < 2; ++m)
                    wn_[m] = *reinterpret_cast<const bf16x8*>(
                        W3p + ((((kk + 1) * 8 + wn * 2 + m) << 6) + lane) * 8);
            }
            const int k = kk * 32 + lhi * 8;
            bf16x8 xf[4];
            #pragma unroll
            for (int n = 0; n < 4; ++n) {
                int r = n * 16 + l15;
                xf[n] = *reinterpret_cast<const bf16x8*>(
                    &h2s[r * 512 + ((k * 2) ^ ((r & 15) << 4))]);
            }
            __builtin_amdgcn_s_setprio(1);
            #pragma unroll
            for (int m = 0; m < 2; ++m)
                #pragma unroll
                for (int n = 0; n < 4; ++n)
                    acc3[m][n] = __builtin_amdgcn_mfma_f32_16x16x32_bf16(
                        wc2[m], xf[n], acc3[m][n], 0, 0, 0);
            __builtin_amdgcn_s_setprio(0);
            #pragma unroll
            for (int m = 0; m < 2; ++m) wc2[m] = wn_[m];
        }
    }

    // ================= fused LayerNorm epilogue (h3 in registers) ===========
    #pragma unroll
    for (int m = 0; m < 2; ++m) {
        int f = wn * 32 + m * 16 + lhi * 4;
        f32x4 bb = *reinterpret_cast<const f32x4*>(b3 + f);
        #pragma unroll
        for (int n = 0; n < 4; ++n) {
            f32x4 v = acc3[m][n];
            v.x = lrelu(v.x + bb.x); v.y = lrelu(v.y + bb.y);
            v.z = lrelu(v.z + bb.z); v.w = lrelu(v.w + bb.w);
            acc3[m][n] = v;
        }
    }
    // per-edge partials over this wave's 32 feats: reduce across lhi (bits 4,5)
    #pragma unroll
    for (int n = 0; n < 4; ++n) {
        float s = 0.f, s2 = 0.f;
        #pragma unroll
        for (int m = 0; m < 2; ++m) {
            f32x4 v = acc3[m][n];
            s  += v.x + v.y + v.z + v.w;
            s2 += v.x * v.x + v.y * v.y + v.z * v.z + v.w * v.w;
        }
        s  += __shfl_xor(s, 16);  s  += __shfl_xor(s, 32);
        s2 += __shfl_xor(s2, 16); s2 += __shfl_xor(s2, 32);
        if (lhi == 0) {
            lnp[n * 16 + l15][wn][0] = s;
            lnp[n * 16 + l15][wn][1] = s2;
        }
    }
    __syncthreads();   // partials visible (h2s reads also complete)
    {
        const int f0 = wn * 32 + lhi * 4;
        const int f1 = f0 + 16;
        f32x4 gam0 = *reinterpret_cast<const f32x4*>(gamma + f0);
        f32x4 gam1 = *reinterpret_cast<const f32x4*>(gamma + f1);
        f32x4 bet0 = *reinterpret_cast<const f32x4*>(beta + f0);
        f32x4 bet1 = *reinterpret_cast<const f32x4*>(beta + f1);
        #pragma unroll
        for (int n = 0; n < 4; ++n) {
            int e = n * 16 + l15;
            f32x4 pa = *reinterpret_cast<const f32x4*>(&lnp[e][0][0]);
            f32x4 pb = *reinterpret_cast<const f32x4*>(&lnp[e][2][0]);
            float s    = pa.x + pa.z + pb.x + pb.z;
            float s2   = pa.y + pa.w + pb.y + pb.w;
            float mean = s * (1.f / 128.f);
            float var  = s2 * (1.f / 128.f) - mean * mean;
            float rstd = rsqrtf(var + 1e-5f);
            int rg = m0 + e;
            if (EXACT || rg < E) {
                float* op = out + (size_t)rg * 128;
                f32x4 v0 = acc3[0][n], v1 = acc3[1][n];
                f32x4 o0, o1;
                o0.x = (v0.x - mean) * rstd * gam0.x + bet0.x;
                o0.y = (v0.y - mean) * rstd * gam0.y + bet0.y;
                o0.z = (v0.z - mean) * rstd * gam0.z + bet0.z;
                o0.w = (v0.w - mean) * rstd * gam0.w + bet0.w;
                o1.x = (v1.x - mean) * rstd * gam1.x + bet1.x;
                o1.y = (v1.y - mean) * rstd * gam1.y + bet1.y;
                o1.z = (v1.z - mean) * rstd * gam1.z + bet1.z;
                o1.w = (v1.w - mean) * rstd * gam1.w + bet1.w;
                *reinterpret_cast<f32x4*>(op + f0) = o0;
                *reinterpret_cast<f32x4*>(op + f1) = o1;
            }
        }
    }
}

extern "C" void kernel_launch(void* const* d_in, const int* in_sizes, int n_in,
                              void* d_out, int out_size, void* d_ws, size_t ws_size,
                              hipStream_t stream) {
    const float* src  = (const float*)d_in[0];
    const float* dst  = (const float*)d_in[1];
    const float* ea   = (const float*)d_in[2];
    const float* u    = (const float*)d_in[3];
    const int*   bat  = (const int*)d_in[4];
    const float* W1   = (const float*)d_in[5];
    const float* b1   = (const float*)d_in[6];
    const float* W2   = (const float*)d_in[7];
    const float* b2   = (const float*)d_in[8];
    const float* W3   = (const float*)d_in[9];
    const float* b3   = (const float*)d_in[10];
    const float* gam  = (const float*)d_in[11];
    const float* bet  = (const float*)d_in[12];
    float* out = (float*)d_out;
    unsigned short* Wp = (unsigned short*)d_ws;   // 458752 B used

    const int E = in_sizes[0] / 128;

    prep_pack<<<896, 256, 0, stream>>>(W1, W2, W3, Wp);
    const int nblk = (E + 63) / 64;
    if ((E & 63) == 0)
        edge_mlp<true><<<nblk, 256, 0, stream>>>(src, dst, ea, u, bat, Wp,
                                                 b1, b2, b3, gam, bet, out, E);
    else
        edge_mlp<false><<<nblk, 256, 0, stream>>>(src, dst, ea, u, bat, Wp,
                                                  b1, b2, b3, gam, bet, out, E);
}